// Round 7
// baseline (318.631 us; speedup 1.0000x reference)
//
#include <hip/hip_runtime.h>
#include <hip/hip_bf16.h>

#define B_ 2
#define S_ 2048
#define H_ 2048
#define NH_ 16
#define NKV_ 4
#define HD_ 128
#define M_ (B_*S_)
#define KVD_ (NKV_*HD_)

typedef signed char s8;
typedef __attribute__((ext_vector_type(8))) short short8;
typedef __attribute__((ext_vector_type(4))) float f32x4;
typedef __attribute__((ext_vector_type(4))) int int4v;

__device__ __forceinline__ float loadf(const void* p, long i, int isb){
  if (isb) return __bfloat162float(((const __hip_bfloat16*)p)[i]);
  return ((const float*)p)[i];
}

__device__ __forceinline__ unsigned short f2bf(float f){
  union { float f; unsigned u; } v; v.f = f;
  unsigned r = v.u + 0x7FFF + ((v.u >> 16) & 1);
  return (unsigned short)(r >> 16);
}

__device__ __forceinline__ float bf2f(unsigned short b){
  union { unsigned u; float f; } v; v.u = ((unsigned)b) << 16; return v.f;
}

// async global->LDS, 16B/lane; lds dst = wave-uniform base + lane*16
__device__ __forceinline__ void gl2lds16(const void* g, void* l){
  __builtin_amdgcn_global_load_lds(
      (const __attribute__((address_space(1))) void*)g,
      (__attribute__((address_space(3))) void*)l, 16, 0, 0);
}

// ---- dtype sniffer ----
__global__ void k_detect(const unsigned int* x, int* flag){
  __shared__ int sh[256];
  int t = threadIdx.x, c = 0;
  for (int i = t; i < 2048; i += 256){
    unsigned e = (x[i] >> 7) & 0xFF;
    if (e >= 90 && e <= 150) c++;
  }
  sh[t] = c; __syncthreads();
  for (int k = 128; k > 0; k >>= 1){ if (t < k) sh[t] += sh[t+k]; __syncthreads(); }
  if (t == 0) flag[0] = (sh[0] > 1228) ? 1 : 0;
}

// ---- fused: RoPE cos/sin table + sum|w| over all 4 weights (grid 2048) ----
__global__ void k_prep(const void* Wq, const void* Wk, const void* Wv, const void* Wo,
                       const int* flag, float* wsum, float* ct, float* st){
  int bid = blockIdx.x, t = threadIdx.x;
  if (t < 64){
    float inv = exp2f(-(float)t * 0.20762050593045952f);  // 10000^(-d/64)
    float a = (float)bid * inv;
    float sn, cs; sincosf(a, &sn, &cs);
    ct[bid*64 + t] = cs; st[bid*64 + t] = sn;
  }
  __shared__ float sh[256];
  int isb = *flag;
  const void* w; long n; int wi; long b0; int nb;
  if (bid < 768)       { w = Wq; wi = 0; n = (long)H_*H_;   b0 = bid;      nb = 768; }
  else if (bid < 1024) { w = Wk; wi = 1; n = (long)KVD_*H_; b0 = bid-768;  nb = 256; }
  else if (bid < 1280) { w = Wv; wi = 2; n = (long)KVD_*H_; b0 = bid-1024; nb = 256; }
  else                 { w = Wo; wi = 3; n = (long)H_*H_;   b0 = bid-1280; nb = 768; }
  float s = 0.f;
  for (long i = b0*256 + t; i < n; i += (long)nb*256) s += fabsf(loadf(w, i, isb));
  sh[t] = s; __syncthreads();
  for (int k = 128; k > 0; k >>= 1){ if (t < k) sh[t] += sh[t+k]; __syncthreads(); }
  if (t == 0) atomicAdd(&wsum[wi], sh[0]);
}

// ---- fused ternary weight quant over all 4 weights (scale from wsum inline) ----
__global__ void k_wquant_all(const void* Wq, const void* Wk, const void* Wv, const void* Wo,
                             const int* flag, const float* wsum,
                             s8* oq, s8* ok, s8* ov, s8* oo){
  int isb = *flag;
  int bid = blockIdx.x, t = threadIdx.x;
  const float cntq = (float)((long)H_*H_), cntkv = (float)((long)KVD_*H_);
  const void* w; s8* out; long n; int wi; long b0; int nb; float cnt;
  if (bid < 1024)      { w = Wq; out = oq; wi = 0; n = (long)H_*H_;   b0 = bid;       nb = 1024; cnt = cntq; }
  else if (bid < 1280) { w = Wk; out = ok; wi = 1; n = (long)KVD_*H_; b0 = bid-1024;  nb = 256;  cnt = cntkv; }
  else if (bid < 1536) { w = Wv; out = ov; wi = 2; n = (long)KVD_*H_; b0 = bid-1280;  nb = 256;  cnt = cntkv; }
  else                 { w = Wo; out = oo; wi = 3; n = (long)H_*H_;   b0 = bid-1536;  nb = 1024; cnt = cntq; }
  float mean = fmaxf(wsum[wi] / cnt, 1e-5f);
  float sc = 1.0f / mean;
  for (long i = b0*256 + t; i < n; i += (long)nb*256){
    float v = rintf(loadf(w, i, isb) * sc);
    v = fminf(fmaxf(v, -1.f), 1.f);
    out[i] = (s8)v;
  }
}

// ---- per-token activation quant, single pass (typed input) ----
__global__ void k_aquant_in(const void* x, const int* flag, float* srow, s8* xq){
  __shared__ float sh[256];
  int isb = *flag; int r = blockIdx.x, t = threadIdx.x;
  long base = (long)r * H_;
  float v[8];
  if (isb){
    uint4 wv = ((const uint4*)((const unsigned short*)x + base))[t];
    unsigned u[4] = {wv.x, wv.y, wv.z, wv.w};
    #pragma unroll
    for (int i = 0; i < 4; i++){
      v[2*i]   = bf2f((unsigned short)(u[i] & 0xFFFF));
      v[2*i+1] = bf2f((unsigned short)(u[i] >> 16));
    }
  } else {
    const float4* p = (const float4*)((const float*)x + base);
    float4 a = p[t*2], b2 = p[t*2+1];
    v[0]=a.x; v[1]=a.y; v[2]=a.z; v[3]=a.w; v[4]=b2.x; v[5]=b2.y; v[6]=b2.z; v[7]=b2.w;
  }
  float mx = 0.f;
  #pragma unroll
  for (int i = 0; i < 8; i++) mx = fmaxf(mx, fabsf(v[i]));
  sh[t] = mx; __syncthreads();
  for (int k = 128; k > 0; k >>= 1){ if (t < k) sh[t] = fmaxf(sh[t], sh[t+k]); __syncthreads(); }
  float s = 127.0f / fmaxf(sh[0], 1e-5f);
  if (t == 0) srow[r] = s;
  unsigned long long pk = 0;
  #pragma unroll
  for (int i = 0; i < 8; i++){
    float q = fminf(fmaxf(rintf(v[i] * s), -128.f), 127.f);
    pk |= ((unsigned long long)(unsigned char)(s8)q) << (8*i);
  }
  *(unsigned long long*)(xq + base + t*8) = pk;
}

// ---- merge attention partial(s) + per-token activation quant ----
// split mode (lp1 != null): partial p holds normalized n_p (bf16) and
// denominator l_p (fp32 per row*head); merged = (n0*l0 + n1*l1)/(l0+l1).
// l0 > 0 always (split 0 includes the diagonal chunk).
// single mode (lp1 == null): x0 is already the full normalized output.
__global__ void k_aquant_bf16(const unsigned short* __restrict__ x0,
                              const unsigned short* __restrict__ x1,
                              const float* __restrict__ lp0, const float* __restrict__ lp1,
                              float* __restrict__ srow, s8* __restrict__ xq){
  __shared__ float sh[256];
  int r = blockIdx.x, t = threadIdx.x;
  long base = (long)r * H_;
  float v[8];
  uint4 a0 = ((const uint4*)(x0 + base))[t];
  unsigned u0[4] = {a0.x, a0.y, a0.z, a0.w};
  if (lp1){
    int h = t >> 4;                   // 8 elems/thread, 128/head
    float l0 = lp0[(long)r*NH_ + h], l1 = lp1[(long)r*NH_ + h];
    float inv = 1.0f / (l0 + l1);
    float w0 = l0 * inv, w1 = l1 * inv;
    uint4 a1 = ((const uint4*)(x1 + base))[t];
    unsigned u1[4] = {a1.x, a1.y, a1.z, a1.w};
    #pragma unroll
    for (int i = 0; i < 4; i++){
      v[2*i]   = bf2f((unsigned short)(u0[i] & 0xFFFF))*w0 + bf2f((unsigned short)(u1[i] & 0xFFFF))*w1;
      v[2*i+1] = bf2f((unsigned short)(u0[i] >> 16))*w0   + bf2f((unsigned short)(u1[i] >> 16))*w1;
    }
  } else {
    #pragma unroll
    for (int i = 0; i < 4; i++){
      v[2*i]   = bf2f((unsigned short)(u0[i] & 0xFFFF));
      v[2*i+1] = bf2f((unsigned short)(u0[i] >> 16));
    }
  }
  float mx = 0.f;
  #pragma unroll
  for (int i = 0; i < 8; i++) mx = fmaxf(mx, fabsf(v[i]));
  sh[t] = mx; __syncthreads();
  for (int k = 128; k > 0; k >>= 1){ if (t < k) sh[t] = fmaxf(sh[t], sh[t+k]); __syncthreads(); }
  float s = 127.0f / fmaxf(sh[0], 1e-5f);
  if (t == 0) srow[r] = s;
  unsigned long long pk = 0;
  #pragma unroll
  for (int i = 0; i < 8; i++){
    float q = fminf(fmaxf(rintf(v[i] * s), -128.f), 127.f);
    pk |= ((unsigned long long)(unsigned char)(s8)q) << (8*i);
  }
  *(unsigned long long*)(xq + base + t*8) = pk;
}

// ---- MFMA int8 GEMM core: C[m][n] = sum_k A[m][k]*Bw[n][k] ----
// (r2 form: single LDS buffer, 2 barriers/K-step — dbuf was neutral, r3)
// arow is a parameter: callers compute it from the XCD-swizzled block id.
// mode 0: RoPE + (1/sqrt(HD))*log2(e) -> bf16 Qb;  mode 3: RoPE -> bf16 Kb
// mode 1: bf16 Vt[b][col][S];          mode 2: isb-dtype final out
__device__ __forceinline__ void gemm_core(
      const s8* __restrict__ A, const s8* __restrict__ Bw, s8* As, s8* Bs,
      const float* __restrict__ srow, float mean,
      void* __restrict__ Cout, int N, int mode, int isb,
      unsigned short* __restrict__ Vt,
      const float* __restrict__ ct, const float* __restrict__ st,
      long bcol, long arow){
  int tid = threadIdx.x;
  int wave = tid >> 6, lane = tid & 63;
  int quad = lane >> 4, c = lane & 15;
  int wm = wave >> 1, wn = wave & 1;
  const int K = H_;

  int4v acc[4][4];
  #pragma unroll
  for (int mt = 0; mt < 4; mt++)
    #pragma unroll
    for (int nt = 0; nt < 4; nt++) acc[mt][nt] = (int4v){0,0,0,0};

  int rl = lane >> 2;
  int kq = (lane & 3) ^ ((lane >> 3) & 3);
  int ch0 = wave*2, ch1 = wave*2 + 1;
  long gA0 = (arow + ch0*16 + rl)*(long)K + kq*16;
  long gA1 = (arow + ch1*16 + rl)*(long)K + kq*16;
  long gB0 = (bcol + ch0*16 + rl)*(long)K + kq*16;
  long gB1 = (bcol + ch1*16 + rl)*(long)K + kq*16;

  int sA = quad ^ ((c >> 1) & 3);
  int ntl[4];
  #pragma unroll
  for (int nt = 0; nt < 4; nt++) ntl[nt] = 2*wn + (nt & 1) + 4*(nt >> 1);
  int frA[4], frB[4];
  #pragma unroll
  for (int mt = 0; mt < 4; mt++) frA[mt] = (wm*64 + mt*16 + c)*64 + sA*16;
  #pragma unroll
  for (int nt = 0; nt < 4; nt++) frB[nt] = (ntl[nt]*16 + c)*64 + sA*16;

  for (int k0 = 0; k0 < K; k0 += 64){
    gl2lds16(A  + gA0 + k0, As + ch0*1024);
    gl2lds16(A  + gA1 + k0, As + ch1*1024);
    gl2lds16(Bw + gB0 + k0, Bs + ch0*1024);
    gl2lds16(Bw + gB1 + k0, Bs + ch1*1024);
    __syncthreads();
    int4v afr[4], bfr[4];
    #pragma unroll
    for (int mt = 0; mt < 4; mt++) afr[mt] = *(const int4v*)&As[frA[mt]];
    #pragma unroll
    for (int nt = 0; nt < 4; nt++) bfr[nt] = *(const int4v*)&Bs[frB[nt]];
    #pragma unroll
    for (int mt = 0; mt < 4; mt++)
      #pragma unroll
      for (int nt = 0; nt < 4; nt++)
        acc[mt][nt] = __builtin_amdgcn_mfma_i32_16x16x64_i8(afr[mt], bfr[nt], acc[mt][nt], 0, 0, 0);
    __syncthreads();
  }

  if (mode == 0 || mode == 3){
    unsigned short* Ob = (unsigned short*)Cout;
    #pragma unroll
    for (int mt = 0; mt < 4; mt++){
      #pragma unroll
      for (int r = 0; r < 4; r++){
        long grow = arow + wm*64 + mt*16 + quad*4 + r;
        float sc = mean / srow[grow];
        // fold softmax scale AND log2(e) into Q so attention can use exp2:
        // 2^-3.5 * log2(e) = 0.12751743
        if (mode == 0) sc *= 0.12751743f;
        int pos = (int)(grow & (S_-1));
        #pragma unroll
        for (int p = 0; p < 2; p++){
          int col_lo = (int)bcol + (2*wn + p)*16 + c;
          int d = col_lo & 63;
          float cv = ct[pos*64 + d], sv = st[pos*64 + d];
          float vlo = acc[mt][p][r]   * sc;
          float vhi = acc[mt][p+2][r] * sc;
          Ob[grow*(long)N + col_lo]      = f2bf(vlo*cv - vhi*sv);
          Ob[grow*(long)N + col_lo + 64] = f2bf(vhi*cv + vlo*sv);
        }
      }
    }
  } else if (mode == 1){
    #pragma unroll
    for (int mt = 0; mt < 4; mt++){
      #pragma unroll
      for (int r = 0; r < 4; r++){
        long grow = arow + wm*64 + mt*16 + quad*4 + r;
        float sc = mean / srow[grow];
        long bb = grow >> 11; int sI = (int)(grow & (S_-1));
        unsigned short* base = Vt + bb*(long)KVD_*S_ + sI;
        #pragma unroll
        for (int nt = 0; nt < 4; nt++)
          base[(long)(bcol + ntl[nt]*16 + c)*S_] = f2bf(acc[mt][nt][r] * sc);
      }
    }
  } else {
    #pragma unroll
    for (int mt = 0; mt < 4; mt++){
      #pragma unroll
      for (int r = 0; r < 4; r++){
        long grow = arow + wm*64 + mt*16 + quad*4 + r;
        float sc = mean / srow[grow];
        long cb = grow*(long)N + bcol + c;
        if (isb){
          __hip_bfloat16* o = (__hip_bfloat16*)Cout;
          #pragma unroll
          for (int nt = 0; nt < 4; nt++)
            o[cb + ntl[nt]*16] = __float2bfloat16(acc[mt][nt][r] * sc);
        } else {
          float* o = (float*)Cout;
          #pragma unroll
          for (int nt = 0; nt < 4; nt++)
            o[cb + ntl[nt]*16] = acc[mt][nt][r] * sc;
        }
      }
    }
  }
}

// ---- fused QKV GEMM: flat grid 768 with XCD panel clustering (r6 form) ----
__global__ __launch_bounds__(256, 2) void k_gemm_qkv(
      const s8* __restrict__ xq,
      const s8* __restrict__ wqq, const s8* __restrict__ wkq, const s8* __restrict__ wvq,
      const float* __restrict__ srow, const float* __restrict__ wsum,
      unsigned short* __restrict__ Qb, unsigned short* __restrict__ Kb,
      unsigned short* __restrict__ Vt,
      const float* __restrict__ ct, const float* __restrict__ st){
  __shared__ __align__(16) s8 As[128*64];
  __shared__ __align__(16) s8 Bs[128*64];
  int lid = blockIdx.x;
  int xcd = lid & 7;
  int rem = lid >> 3;          // 0..95
  int by  = xcd*4 + (rem & 3); // 0..31
  int bx  = rem >> 2;          // 0..23
  const float cntq = (float)((long)H_*H_), cntkv = (float)((long)KVD_*H_);
  const s8* Bw; void* Cout; unsigned short* vt = nullptr;
  int N, mode; float mean; long bcol;
  if (bx < 16){
    Bw = wqq; Cout = Qb; N = H_;   mode = 0; mean = fmaxf(wsum[0]/cntq, 1e-5f);  bcol = (long)bx*128;
  } else if (bx < 20){
    Bw = wkq; Cout = Kb; N = KVD_; mode = 3; mean = fmaxf(wsum[1]/cntkv, 1e-5f); bcol = (long)(bx-16)*128;
  } else {
    Bw = wvq; Cout = nullptr; vt = Vt; N = KVD_; mode = 1; mean = fmaxf(wsum[2]/cntkv, 1e-5f); bcol = (long)(bx-20)*128;
  }
  gemm_core(xq, Bw, As, Bs, srow, mean, Cout, N, mode, 0, vt, ct, st, bcol, (long)by*128);
}

// ---- output GEMM: flat grid 512 with the same clustering ----
__global__ __launch_bounds__(256, 2) void k_gemm_o(
      const s8* __restrict__ aq, const s8* __restrict__ woq,
      const float* __restrict__ srow, const float* __restrict__ wsum,
      const int* __restrict__ flag, void* __restrict__ out,
      const float* __restrict__ ct, const float* __restrict__ st){
  __shared__ __align__(16) s8 As[128*64];
  __shared__ __align__(16) s8 Bs[128*64];
  int lid = blockIdx.x;
  int xcd = lid & 7;
  int rem = lid >> 3;          // 0..63
  int by  = xcd*4 + (rem & 3); // 0..31
  int bx  = rem >> 2;          // 0..15
  float mean = fmaxf(wsum[3] / (float)((long)H_*H_), 1e-5f);
  gemm_core(aq, woq, As, Bs, srow, mean, out, H_, 2, *flag, nullptr, ct, st,
            (long)bx*128, (long)by*128);
}

// ---- MFMA flash attention v10: split x2 + clustering + balanced pairing ----
// r5 proved the split mechanism (occupancy 12.6->30.8%) but launch_bounds
// (256,4) forced regs 64 -> ~1GB spill. Natural allocation is 124 unified
// regs -> 4 waves/SIMD fit WITHOUT forcing. r6 proved clustering (FETCH
// 39.5->12.4MB) but dropped the work-pairing (+9us imbalance).
// This kernel: grid 512*nsplit flat. panel = lid&7 -> one (b,kvh) per XCD
// (all co-resident blocks share a 3MB L2 working set). j = lid>>3;
// sp = j>>6 (nsplit2); w = j&63; win = w<32 ? w : 95-w  -- a CU's blocks
// {j0, j0+32(, j0+64, j0+96)} get windows {j0, 63-j0} x splits -> constant
// per-CU work. No running max (plain exp2 sums) -> split partials merge
// additively via (n0*l0+n1*l1)/(l0+l1) in k_aquant_bf16.
// Single Ks buffer restage (37KB LDS): issued after barrier B, in flight
// during PV, drained at next barrier A.
#define PSTR 40
__global__ __launch_bounds__(256) void k_attn_mfma(const unsigned short* __restrict__ Qb,
    const unsigned short* __restrict__ Kb, const unsigned short* __restrict__ Vt,
    unsigned short* __restrict__ on0, unsigned short* __restrict__ on1,
    float* __restrict__ lp0, float* __restrict__ lp1, int nsplit){
  int wid = threadIdx.x >> 6, lane = threadIdx.x & 63;
  int quad = lane >> 4, c = lane & 15;
  int lid = blockIdx.x;
  int panel = lid & 7;           // -> XCD under id%8 round-robin
  int kvh = panel & 3, b = panel >> 2;
  int j = lid >> 3;
  int sp = (nsplit == 2) ? (j >> 6) : 0;
  int w = j & 63;
  int win = (w < 32) ? w : 95 - w;   // balanced pairing within panel
  int h = kvh*4 + wid;
  int q0 = win*32;
  int kstep = nsplit*64;

  __shared__ __align__(16) unsigned short Ks[64*128];
  __shared__ __align__(16) unsigned short Vs[128*64];
  __shared__ __align__(16) unsigned short Ps[4][16*PSTR];

  unsigned short* on = sp ? on1 : on0;
  float*          lp = sp ? lp1 : lp0;

  short8 qf[2][4];
  #pragma unroll
  for (int t0 = 0; t0 < 2; t0++)
    #pragma unroll
    for (int f = 0; f < 4; f++)
      qf[t0][f] = *(const short8*)(Qb + ((long)(b*S_ + q0 + t0*16 + c)*NH_ + h)*HD_ + f*32 + quad*8);

  const unsigned short* Kg = Kb + (long)b*S_*KVD_ + kvh*HD_;
  const unsigned short* Vg = Vt + ((long)b*KVD_ + kvh*HD_)*S_;

  f32x4 o[2][8], ol[2];
  #pragma unroll
  for (int t0 = 0; t0 < 2; t0++){
    #pragma unroll
    for (int i = 0; i < 8; i++) o[t0][i] = (f32x4){0.f,0.f,0.f,0.f};
    ol[t0] = (f32x4){0.f,0.f,0.f,0.f};
  }
  short8 ones;
  #pragma unroll
  for (int i = 0; i < 8; i++) ones[i] = (short)0x3F80;

  int skey = lane >> 4;
  int kslot = lane & 15;
  int vrow = lane >> 3;
  int vslot = lane & 7;

  int nk = q0 + 32;
  int kc0 = sp * 64;

  if (kc0 < nk){
    // prologue: stage K(kc0) -> Ks
    #pragma unroll
    for (int i = 0; i < 4; i++){
      int kk = wid*16 + i*4;
      int key = kk + skey;
      int g = kslot ^ (key & 15);
      gl2lds16(Kg + (long)(kc0 + key)*KVD_ + g*8, &Ks[kk*128]);
    }

    for (int kc = kc0; kc < nk; kc += kstep){
      __syncthreads();   // A: K(kc) staged; all waves done with prior Vs reads
      // stage V(kc) — latency hidden by QK phase below, drained at barrier B
      #pragma unroll
      for (int i = 0; i < 4; i++){
        int rr = wid*32 + i*8;
        int hd = rr + vrow;
        int g = vslot ^ (hd & 7);
        gl2lds16(Vg + (long)hd*S_ + kc + g*8, &Vs[rr*64]);
      }

      // ---- QK^T from Ks, SWAPPED: s[t0][kt] = K_tile^T x Q_tile
      // layout: s[t0][kt][r] = S[key = kc+kt*16+quad*4+r][q = q0+t0*16+c]
      f32x4 s[2][4];
      #pragma unroll
      for (int t0 = 0; t0 < 2; t0++)
        #pragma unroll
        for (int kt = 0; kt < 4; kt++) s[t0][kt] = (f32x4){0.f,0.f,0.f,0.f};
      #pragma unroll
      for (int kt = 0; kt < 4; kt++){
        short8 kf4[4];
        #pragma unroll
        for (int f = 0; f < 4; f++)
          kf4[f] = *(const short8*)&Ks[(kt*16 + c)*128 + ((f*4 + quad) ^ c)*8];
        #pragma unroll
        for (int t0 = 0; t0 < 2; t0++)
          #pragma unroll
          for (int f = 0; f < 4; f++)
            s[t0][kt] = __builtin_amdgcn_mfma_f32_16x16x32_bf16(kf4[f], qf[t0][f], s[t0][kt], 0, 0, 0);
      }
      // causal mask in transposed layout
      #pragma unroll
      for (int t0 = 0; t0 < 2; t0++){
        int qv = q0 + t0*16 + c;
        if (kc + 63 > q0 + t0*16){
          #pragma unroll
          for (int kt = 0; kt < 4; kt++){
            #pragma unroll
            for (int r = 0; r < 4; r++){
              int key = kc + kt*16 + quad*4 + r;
              if (key > qv) s[t0][kt][r] = -1e30f;
            }
          }
        }
      }

      __syncthreads();   // B: V(kc) staged (hidden by QK above); Ks reads done

      // restage K(kc+kstep) into same Ks buffer; in flight during PV,
      // drained at next barrier A (nothing reads Ks until then)
      if (kc + kstep < nk){
        #pragma unroll
        for (int i = 0; i < 4; i++){
          int kk = wid*16 + i*4;
          int key = kk + skey;
          int g = kslot ^ (key & 15);
          gl2lds16(Kg + (long)(kc + kstep + key)*KVD_ + g*8, &Ks[kk*128]);
        }
      }

      // ---- exp2 + packed P write + PV
      #pragma unroll
      for (int pp = 0; pp < 2; pp++){
        short8 vf[8];
        #pragma unroll
        for (int nt = 0; nt < 8; nt++)
          vf[nt] = *(const short8*)&Vs[(nt*16 + c)*64 + ((pp*4 + quad) ^ (c & 7))*8];
        #pragma unroll
        for (int t0 = 0; t0 < 2; t0++){
          #pragma unroll
          for (int tk = 0; tk < 2; tk++){
            f32x4 sv = s[t0][pp*2 + tk];
            float e0 = exp2f(sv[0]), e1 = exp2f(sv[1]);
            float e2 = exp2f(sv[2]), e3 = exp2f(sv[3]);
            unsigned w0, w1;
            asm("v_cvt_pk_bf16_f32 %0, %1, %2" : "=v"(w0) : "v"(e0), "v"(e1));
            asm("v_cvt_pk_bf16_f32 %0, %1, %2" : "=v"(w1) : "v"(e2), "v"(e3));
            uint2 pkv; pkv.x = w0; pkv.y = w1;
            // 4 consecutive keys for q-row c -> one 8B store
            *(uint2*)&Ps[wid][c*PSTR + tk*16 + quad*4] = pkv;
          }
          short8 pf = *(const short8*)&Ps[wid][c*PSTR + quad*8];
          #pragma unroll
          for (int nt = 0; nt < 8; nt++)
            o[t0][nt] = __builtin_amdgcn_mfma_f32_16x16x32_bf16(pf, vf[nt], o[t0][nt], 0, 0, 0);
          ol[t0] = __builtin_amdgcn_mfma_f32_16x16x32_bf16(pf, ones, ol[t0], 0, 0, 0);
        }
      }
    }
  }

  // epilogue: normalized partial + denominator (zero-work blocks write 0s)
  #pragma unroll
  for (int t0 = 0; t0 < 2; t0++){
    float il[4];
    #pragma unroll
    for (int r = 0; r < 4; r++) il[r] = ol[t0][r] > 0.f ? 1.0f / ol[t0][r] : 0.f;
    #pragma unroll
    for (int r = 0; r < 4; r++){
      long row = (long)(b*S_ + q0 + t0*16 + quad*4 + r);
      lp[row*NH_ + h] = ol[t0][r];   // 16 lanes write same value: benign
      #pragma unroll
      for (int nt = 0; nt < 8; nt++)
        on[row*H_ + h*HD_ + nt*16 + c] = f2bf(o[t0][nt][r]*il[r]);
    }
  }
}

extern "C" void kernel_launch(void* const* d_in, const int* in_sizes, int n_in,
                              void* d_out, int out_size, void* d_ws, size_t ws_size,
                              hipStream_t stream){
  (void)in_sizes; (void)n_in; (void)out_size;
  const void* x  = d_in[0];
  const void* Wq = d_in[2];
  const void* Wk = d_in[3];
  const void* Wv = d_in[4];
  const void* Wo = d_in[5];
  char* ws = (char*)d_ws;
  size_t o = 0;
  auto alloc = [&](size_t b){ size_t r = o; o += (b + 255) & ~(size_t)255; return r; };
  size_t META = alloc(256);
  float* wsum = (float*)(ws + META);
  int*   flag = (int*)  (ws + META + 32);
  float* s_x = (float*)(ws + alloc((size_t)M_*4));
  float* s_a = (float*)(ws + alloc((size_t)M_*4));
  float* ct  = (float*)(ws + alloc((size_t)S_*64*4));
  float* st  = (float*)(ws + alloc((size_t)S_*64*4));
  s8* xq  = (s8*)(ws + alloc((size_t)M_*H_));
  s8* wqq = (s8*)(ws + alloc((size_t)H_*H_));
  s8* wkq = (s8*)(ws + alloc((size_t)KVD_*H_));
  s8* wvq = (s8*)(ws + alloc((size_t)KVD_*H_));
  s8* woq = (s8*)(ws + alloc((size_t)H_*H_));
  unsigned short* Qb = (unsigned short*)(ws + alloc((size_t)M_*NH_*HD_*2));
  unsigned short* Kb = (unsigned short*)(ws + alloc((size_t)M_*KVD_*2));
  unsigned short* Vt = (unsigned short*)(ws + alloc((size_t)M_*KVD_*2));
  unsigned short* ab0 = (unsigned short*)(ws + alloc((size_t)M_*H_*2));
  float* lp0 = (float*)(ws + alloc((size_t)M_*NH_*4));
  s8* aq = xq;   // xq dead after QKV GEMM

  // KV-split partials only if workspace has room (r4 lesson: never allocate
  // past ws_size). r5 confirmed the split path engages and is numerically OK.
  size_t need1 = ((size_t)M_*H_*2 + 255) & ~(size_t)255;
  size_t need2 = ((size_t)M_*NH_*4 + 255) & ~(size_t)255;
  int nsplit = 1;
  unsigned short* ab1 = nullptr;
  float* lp1 = nullptr;
  if (ws_size >= o + need1 + need2){
    ab1 = (unsigned short*)(ws + alloc((size_t)M_*H_*2));
    lp1 = (float*)(ws + alloc((size_t)M_*NH_*4));
    nsplit = 2;
  }

  hipMemsetAsync(ws + META, 0, 64, stream);
  k_detect<<<1,256,0,stream>>>((const unsigned int*)x, flag);
  k_prep<<<2048,256,0,stream>>>(Wq, Wk, Wv, Wo, flag, wsum, ct, st);
  k_wquant_all<<<2560,256,0,stream>>>(Wq, Wk, Wv, Wo, flag, wsum, wqq, wkq, wvq, woq);
  k_aquant_in<<<M_,256,0,stream>>>(x, flag, s_x, xq);

  k_gemm_qkv<<<768, 256, 0, stream>>>(xq, wqq, wkq, wvq, s_x, wsum, Qb, Kb, Vt, ct, st);

  k_attn_mfma<<<512*nsplit, 256, 0, stream>>>(Qb, Kb, Vt, ab0, ab1, lp0, lp1, nsplit);

  k_aquant_bf16<<<M_,256,0,stream>>>(ab0, ab1, lp0, lp1, s_a, aq);

  k_gemm_o<<<512, 256, 0, stream>>>(aq, woq, s_a, wsum, flag, d_out, ct, st);
}

// Round 8
// 307.939 us; speedup vs baseline: 1.0347x; 1.0347x over previous
//
#include <hip/hip_runtime.h>
#include <hip/hip_bf16.h>

#define B_ 2
#define S_ 2048
#define H_ 2048
#define NH_ 16
#define NKV_ 4
#define HD_ 128
#define M_ (B_*S_)
#define KVD_ (NKV_*HD_)

typedef signed char s8;
typedef __attribute__((ext_vector_type(8))) short short8;
typedef __attribute__((ext_vector_type(4))) float f32x4;
typedef __attribute__((ext_vector_type(4))) int int4v;

__device__ __forceinline__ float loadf(const void* p, long i, int isb){
  if (isb) return __bfloat162float(((const __hip_bfloat16*)p)[i]);
  return ((const float*)p)[i];
}

__device__ __forceinline__ unsigned short f2bf(float f){
  union { float f; unsigned u; } v; v.f = f;
  unsigned r = v.u + 0x7FFF + ((v.u >> 16) & 1);
  return (unsigned short)(r >> 16);
}

__device__ __forceinline__ float bf2f(unsigned short b){
  union { unsigned u; float f; } v; v.u = ((unsigned)b) << 16; return v.f;
}

// async global->LDS, 16B/lane; lds dst = wave-uniform base + lane*16
__device__ __forceinline__ void gl2lds16(const void* g, void* l){
  __builtin_amdgcn_global_load_lds(
      (const __attribute__((address_space(1))) void*)g,
      (__attribute__((address_space(3))) void*)l, 16, 0, 0);
}

// ---- dtype sniffer ----
__global__ void k_detect(const unsigned int* x, int* flag){
  __shared__ int sh[256];
  int t = threadIdx.x, c = 0;
  for (int i = t; i < 2048; i += 256){
    unsigned e = (x[i] >> 7) & 0xFF;
    if (e >= 90 && e <= 150) c++;
  }
  sh[t] = c; __syncthreads();
  for (int k = 128; k > 0; k >>= 1){ if (t < k) sh[t] += sh[t+k]; __syncthreads(); }
  if (t == 0) flag[0] = (sh[0] > 1228) ? 1 : 0;
}

// ---- fused: RoPE cos/sin table + sum|w| over all 4 weights (grid 2048) ----
__global__ void k_prep(const void* Wq, const void* Wk, const void* Wv, const void* Wo,
                       const int* flag, float* wsum, float* ct, float* st){
  int bid = blockIdx.x, t = threadIdx.x;
  if (t < 64){
    float inv = exp2f(-(float)t * 0.20762050593045952f);  // 10000^(-d/64)
    float a = (float)bid * inv;
    float sn, cs; sincosf(a, &sn, &cs);
    ct[bid*64 + t] = cs; st[bid*64 + t] = sn;
  }
  __shared__ float sh[256];
  int isb = *flag;
  const void* w; long n; int wi; long b0; int nb;
  if (bid < 768)       { w = Wq; wi = 0; n = (long)H_*H_;   b0 = bid;      nb = 768; }
  else if (bid < 1024) { w = Wk; wi = 1; n = (long)KVD_*H_; b0 = bid-768;  nb = 256; }
  else if (bid < 1280) { w = Wv; wi = 2; n = (long)KVD_*H_; b0 = bid-1024; nb = 256; }
  else                 { w = Wo; wi = 3; n = (long)H_*H_;   b0 = bid-1280; nb = 768; }
  float s = 0.f;
  for (long i = b0*256 + t; i < n; i += (long)nb*256) s += fabsf(loadf(w, i, isb));
  sh[t] = s; __syncthreads();
  for (int k = 128; k > 0; k >>= 1){ if (t < k) sh[t] += sh[t+k]; __syncthreads(); }
  if (t == 0) atomicAdd(&wsum[wi], sh[0]);
}

// ---- fused ternary weight quant over all 4 weights (scale from wsum inline) ----
__global__ void k_wquant_all(const void* Wq, const void* Wk, const void* Wv, const void* Wo,
                             const int* flag, const float* wsum,
                             s8* oq, s8* ok, s8* ov, s8* oo){
  int isb = *flag;
  int bid = blockIdx.x, t = threadIdx.x;
  const float cntq = (float)((long)H_*H_), cntkv = (float)((long)KVD_*H_);
  const void* w; s8* out; long n; int wi; long b0; int nb; float cnt;
  if (bid < 1024)      { w = Wq; out = oq; wi = 0; n = (long)H_*H_;   b0 = bid;       nb = 1024; cnt = cntq; }
  else if (bid < 1280) { w = Wk; out = ok; wi = 1; n = (long)KVD_*H_; b0 = bid-1024;  nb = 256;  cnt = cntkv; }
  else if (bid < 1536) { w = Wv; out = ov; wi = 2; n = (long)KVD_*H_; b0 = bid-1280;  nb = 256;  cnt = cntkv; }
  else                 { w = Wo; out = oo; wi = 3; n = (long)H_*H_;   b0 = bid-1536;  nb = 1024; cnt = cntq; }
  float mean = fmaxf(wsum[wi] / cnt, 1e-5f);
  float sc = 1.0f / mean;
  for (long i = b0*256 + t; i < n; i += (long)nb*256){
    float v = rintf(loadf(w, i, isb) * sc);
    v = fminf(fmaxf(v, -1.f), 1.f);
    out[i] = (s8)v;
  }
}

// ---- per-token activation quant, single pass (typed input) ----
__global__ void k_aquant_in(const void* x, const int* flag, float* srow, s8* xq){
  __shared__ float sh[256];
  int isb = *flag; int r = blockIdx.x, t = threadIdx.x;
  long base = (long)r * H_;
  float v[8];
  if (isb){
    uint4 wv = ((const uint4*)((const unsigned short*)x + base))[t];
    unsigned u[4] = {wv.x, wv.y, wv.z, wv.w};
    #pragma unroll
    for (int i = 0; i < 4; i++){
      v[2*i]   = bf2f((unsigned short)(u[i] & 0xFFFF));
      v[2*i+1] = bf2f((unsigned short)(u[i] >> 16));
    }
  } else {
    const float4* p = (const float4*)((const float*)x + base);
    float4 a = p[t*2], b2 = p[t*2+1];
    v[0]=a.x; v[1]=a.y; v[2]=a.z; v[3]=a.w; v[4]=b2.x; v[5]=b2.y; v[6]=b2.z; v[7]=b2.w;
  }
  float mx = 0.f;
  #pragma unroll
  for (int i = 0; i < 8; i++) mx = fmaxf(mx, fabsf(v[i]));
  sh[t] = mx; __syncthreads();
  for (int k = 128; k > 0; k >>= 1){ if (t < k) sh[t] = fmaxf(sh[t], sh[t+k]); __syncthreads(); }
  float s = 127.0f / fmaxf(sh[0], 1e-5f);
  if (t == 0) srow[r] = s;
  unsigned long long pk = 0;
  #pragma unroll
  for (int i = 0; i < 8; i++){
    float q = fminf(fmaxf(rintf(v[i] * s), -128.f), 127.f);
    pk |= ((unsigned long long)(unsigned char)(s8)q) << (8*i);
  }
  *(unsigned long long*)(xq + base + t*8) = pk;
}

// ---- per-token activation quant (bf16 input: the attention output) ----
__global__ void k_aquant_bf16(const unsigned short* __restrict__ x, float* __restrict__ srow, s8* __restrict__ xq){
  __shared__ float sh[256];
  int r = blockIdx.x, t = threadIdx.x;
  long base = (long)r * H_;
  uint4 wv = ((const uint4*)(x + base))[t];
  unsigned u[4] = {wv.x, wv.y, wv.z, wv.w};
  float v[8];
  #pragma unroll
  for (int i = 0; i < 4; i++){
    v[2*i]   = bf2f((unsigned short)(u[i] & 0xFFFF));
    v[2*i+1] = bf2f((unsigned short)(u[i] >> 16));
  }
  float mx = 0.f;
  #pragma unroll
  for (int i = 0; i < 8; i++) mx = fmaxf(mx, fabsf(v[i]));
  sh[t] = mx; __syncthreads();
  for (int k = 128; k > 0; k >>= 1){ if (t < k) sh[t] = fmaxf(sh[t], sh[t+k]); __syncthreads(); }
  float s = 127.0f / fmaxf(sh[0], 1e-5f);
  if (t == 0) srow[r] = s;
  unsigned long long pk = 0;
  #pragma unroll
  for (int i = 0; i < 8; i++){
    float q = fminf(fmaxf(rintf(v[i] * s), -128.f), 127.f);
    pk |= ((unsigned long long)(unsigned char)(s8)q) << (8*i);
  }
  *(unsigned long long*)(xq + base + t*8) = pk;
}

// ---- MFMA int8 GEMM core: C[m][n] = sum_k A[m][k]*Bw[n][k] ----
// v3: BK=128 per barrier pair. r3 proved loads are latency-hidden (dbuf
// neutral); the remaining candidate cost is the barrier EVENTS themselves
// (wave-sync + vmcnt/lgkm drain each K-step). Staging 2x64 K-slices per
// barrier pair halves barrier count 64->32 and doubles compute per drain.
// LDS 32KB/block (2 slices x (A 8KB + B 8KB)); 2 blocks/CU = 64KB/CU.
// mode 0: RoPE + (1/sqrt(HD))*log2(e) -> bf16 Qb;  mode 3: RoPE -> bf16 Kb
// mode 1: bf16 Vt[b][col][S];          mode 2: isb-dtype final out
__device__ __forceinline__ void gemm_core(
      const s8* __restrict__ A, const s8* __restrict__ Bw, s8* As, s8* Bs,
      const float* __restrict__ srow, float mean,
      void* __restrict__ Cout, int N, int mode, int isb,
      unsigned short* __restrict__ Vt,
      const float* __restrict__ ct, const float* __restrict__ st,
      long bcol, long arow){
  int tid = threadIdx.x;
  int wave = tid >> 6, lane = tid & 63;
  int quad = lane >> 4, c = lane & 15;
  int wm = wave >> 1, wn = wave & 1;
  const int K = H_;

  int4v acc[4][4];
  #pragma unroll
  for (int mt = 0; mt < 4; mt++)
    #pragma unroll
    for (int nt = 0; nt < 4; nt++) acc[mt][nt] = (int4v){0,0,0,0};

  int rl = lane >> 2;
  int kq = (lane & 3) ^ ((lane >> 3) & 3);
  int ch0 = wave*2, ch1 = wave*2 + 1;
  long gA0 = (arow + ch0*16 + rl)*(long)K + kq*16;
  long gA1 = (arow + ch1*16 + rl)*(long)K + kq*16;
  long gB0 = (bcol + ch0*16 + rl)*(long)K + kq*16;
  long gB1 = (bcol + ch1*16 + rl)*(long)K + kq*16;

  int sA = quad ^ ((c >> 1) & 3);
  int ntl[4];
  #pragma unroll
  for (int nt = 0; nt < 4; nt++) ntl[nt] = 2*wn + (nt & 1) + 4*(nt >> 1);
  int frA[4], frB[4];
  #pragma unroll
  for (int mt = 0; mt < 4; mt++) frA[mt] = (wm*64 + mt*16 + c)*64 + sA*16;
  #pragma unroll
  for (int nt = 0; nt < 4; nt++) frB[nt] = (ntl[nt]*16 + c)*64 + sA*16;

  for (int k0 = 0; k0 < K; k0 += 128){
    // stage both 64-wide K-slices of this 128-step
    gl2lds16(A  + gA0 + k0,      As        + ch0*1024);
    gl2lds16(A  + gA1 + k0,      As        + ch1*1024);
    gl2lds16(Bw + gB0 + k0,      Bs        + ch0*1024);
    gl2lds16(Bw + gB1 + k0,      Bs        + ch1*1024);
    gl2lds16(A  + gA0 + k0 + 64, As + 8192 + ch0*1024);
    gl2lds16(A  + gA1 + k0 + 64, As + 8192 + ch1*1024);
    gl2lds16(Bw + gB0 + k0 + 64, Bs + 8192 + ch0*1024);
    gl2lds16(Bw + gB1 + k0 + 64, Bs + 8192 + ch1*1024);
    __syncthreads();
    #pragma unroll
    for (int s = 0; s < 2; s++){
      const s8* Ab = As + s*8192;
      const s8* Bb = Bs + s*8192;
      int4v afr[4], bfr[4];
      #pragma unroll
      for (int mt = 0; mt < 4; mt++) afr[mt] = *(const int4v*)&Ab[frA[mt]];
      #pragma unroll
      for (int nt = 0; nt < 4; nt++) bfr[nt] = *(const int4v*)&Bb[frB[nt]];
      #pragma unroll
      for (int mt = 0; mt < 4; mt++)
        #pragma unroll
        for (int nt = 0; nt < 4; nt++)
          acc[mt][nt] = __builtin_amdgcn_mfma_i32_16x16x64_i8(afr[mt], bfr[nt], acc[mt][nt], 0, 0, 0);
    }
    __syncthreads();
  }

  if (mode == 0 || mode == 3){
    unsigned short* Ob = (unsigned short*)Cout;
    #pragma unroll
    for (int mt = 0; mt < 4; mt++){
      #pragma unroll
      for (int r = 0; r < 4; r++){
        long grow = arow + wm*64 + mt*16 + quad*4 + r;
        float sc = mean / srow[grow];
        // fold softmax scale AND log2(e) into Q so attention can use exp2:
        // 2^-3.5 * log2(e) = 0.12751743
        if (mode == 0) sc *= 0.12751743f;
        int pos = (int)(grow & (S_-1));
        #pragma unroll
        for (int p = 0; p < 2; p++){
          int col_lo = (int)bcol + (2*wn + p)*16 + c;
          int d = col_lo & 63;
          float cv = ct[pos*64 + d], sv = st[pos*64 + d];
          float vlo = acc[mt][p][r]   * sc;
          float vhi = acc[mt][p+2][r] * sc;
          Ob[grow*(long)N + col_lo]      = f2bf(vlo*cv - vhi*sv);
          Ob[grow*(long)N + col_lo + 64] = f2bf(vhi*cv + vlo*sv);
        }
      }
    }
  } else if (mode == 1){
    #pragma unroll
    for (int mt = 0; mt < 4; mt++){
      #pragma unroll
      for (int r = 0; r < 4; r++){
        long grow = arow + wm*64 + mt*16 + quad*4 + r;
        float sc = mean / srow[grow];
        long bb = grow >> 11; int sI = (int)(grow & (S_-1));
        unsigned short* base = Vt + bb*(long)KVD_*S_ + sI;
        #pragma unroll
        for (int nt = 0; nt < 4; nt++)
          base[(long)(bcol + ntl[nt]*16 + c)*S_] = f2bf(acc[mt][nt][r] * sc);
      }
    }
  } else {
    #pragma unroll
    for (int mt = 0; mt < 4; mt++){
      #pragma unroll
      for (int r = 0; r < 4; r++){
        long grow = arow + wm*64 + mt*16 + quad*4 + r;
        float sc = mean / srow[grow];
        long cb = grow*(long)N + bcol + c;
        if (isb){
          __hip_bfloat16* o = (__hip_bfloat16*)Cout;
          #pragma unroll
          for (int nt = 0; nt < 4; nt++)
            o[cb + ntl[nt]*16] = __float2bfloat16(acc[mt][nt][r] * sc);
        } else {
          float* o = (float*)Cout;
          #pragma unroll
          for (int nt = 0; nt < 4; nt++)
            o[cb + ntl[nt]*16] = acc[mt][nt][r] * sc;
        }
      }
    }
  }
}

// ---- fused QKV GEMM: flat grid 768 with XCD panel clustering (r6 form) ----
__global__ __launch_bounds__(256, 2) void k_gemm_qkv(
      const s8* __restrict__ xq,
      const s8* __restrict__ wqq, const s8* __restrict__ wkq, const s8* __restrict__ wvq,
      const float* __restrict__ srow, const float* __restrict__ wsum,
      unsigned short* __restrict__ Qb, unsigned short* __restrict__ Kb,
      unsigned short* __restrict__ Vt,
      const float* __restrict__ ct, const float* __restrict__ st){
  __shared__ __align__(16) s8 As[2*128*64];
  __shared__ __align__(16) s8 Bs[2*128*64];
  int lid = blockIdx.x;
  int xcd = lid & 7;
  int rem = lid >> 3;          // 0..95
  int by  = xcd*4 + (rem & 3); // 0..31
  int bx  = rem >> 2;          // 0..23
  const float cntq = (float)((long)H_*H_), cntkv = (float)((long)KVD_*H_);
  const s8* Bw; void* Cout; unsigned short* vt = nullptr;
  int N, mode; float mean; long bcol;
  if (bx < 16){
    Bw = wqq; Cout = Qb; N = H_;   mode = 0; mean = fmaxf(wsum[0]/cntq, 1e-5f);  bcol = (long)bx*128;
  } else if (bx < 20){
    Bw = wkq; Cout = Kb; N = KVD_; mode = 3; mean = fmaxf(wsum[1]/cntkv, 1e-5f); bcol = (long)(bx-16)*128;
  } else {
    Bw = wvq; Cout = nullptr; vt = Vt; N = KVD_; mode = 1; mean = fmaxf(wsum[2]/cntkv, 1e-5f); bcol = (long)(bx-20)*128;
  }
  gemm_core(xq, Bw, As, Bs, srow, mean, Cout, N, mode, 0, vt, ct, st, bcol, (long)by*128);
}

// ---- output GEMM: flat grid 512 with the same clustering ----
__global__ __launch_bounds__(256, 2) void k_gemm_o(
      const s8* __restrict__ aq, const s8* __restrict__ woq,
      const float* __restrict__ srow, const float* __restrict__ wsum,
      const int* __restrict__ flag, void* __restrict__ out,
      const float* __restrict__ ct, const float* __restrict__ st){
  __shared__ __align__(16) s8 As[2*128*64];
  __shared__ __align__(16) s8 Bs[2*128*64];
  int lid = blockIdx.x;
  int xcd = lid & 7;
  int rem = lid >> 3;          // 0..63
  int by  = xcd*4 + (rem & 3); // 0..31
  int bx  = rem >> 2;          // 0..15
  float mean = fmaxf(wsum[3] / (float)((long)H_*H_), 1e-5f);
  gemm_core(aq, woq, As, Bs, srow, mean, out, H_, 2, *flag, nullptr, ct, st,
            (long)bx*128, (long)by*128);
}

// ---- MFMA flash attention: r2 configuration VERBATIM (best measured:
// 69.5us, VGPR 128, 2 blocks/CU). 5 rounds of variations (setprio, split,
// clustering, single-buffer, forced occupancy) all measured worse; this
// structure is the empirical optimum at 2-blocks/CU latency plateau.
// Swapped QK (key-contiguous P), exp2 (log2e folded into Q), cvt_pk pairs,
// ds_write_b64 P-store; K double-buffered, V single-buffered; LDS 53KB;
// b==1 window reversal pairs big+small windows per CU.
#define PSTR 40
__global__ __launch_bounds__(256) void k_attn_mfma(const unsigned short* __restrict__ Qb,
    const unsigned short* __restrict__ Kb, const unsigned short* __restrict__ Vt,
    unsigned short* __restrict__ ob){
  int wid = threadIdx.x >> 6, lane = threadIdx.x & 63;
  int quad = lane >> 4, c = lane & 15;
  int kvh = blockIdx.y, b = blockIdx.z;
  int win = blockIdx.x;
  if (b == 1) win = (S_/32 - 1) - win;   // pair big+small windows per CU
  int h = kvh*4 + wid;
  int q0 = win*32;

  __shared__ __align__(16) unsigned short Ks[2][64*128];
  __shared__ __align__(16) unsigned short Vs[128*64];
  __shared__ __align__(16) unsigned short Ps[4][16*PSTR];

  short8 qf[2][4];
  #pragma unroll
  for (int t0 = 0; t0 < 2; t0++)
    #pragma unroll
    for (int f = 0; f < 4; f++)
      qf[t0][f] = *(const short8*)(Qb + ((long)(b*S_ + q0 + t0*16 + c)*NH_ + h)*HD_ + f*32 + quad*8);

  const unsigned short* Kg = Kb + (long)b*S_*KVD_ + kvh*HD_;
  const unsigned short* Vg = Vt + ((long)b*KVD_ + kvh*HD_)*S_;

  f32x4 o[2][8], ol[2];
  #pragma unroll
  for (int t0 = 0; t0 < 2; t0++){
    #pragma unroll
    for (int i = 0; i < 8; i++) o[t0][i] = (f32x4){0.f,0.f,0.f,0.f};
    ol[t0] = (f32x4){0.f,0.f,0.f,0.f};
  }
  short8 ones;
  #pragma unroll
  for (int i = 0; i < 8; i++) ones[i] = (short)0x3F80;

  int skey = lane >> 4;
  int kslot = lane & 15;
  int vrow = lane >> 3;
  int vslot = lane & 7;

  int nk = q0 + 32;
  // prologue: stage K(0) -> Ks[0]
  #pragma unroll
  for (int i = 0; i < 4; i++){
    int kk = wid*16 + i*4;
    int key = kk + skey;
    int g = kslot ^ (key & 15);
    gl2lds16(Kg + (long)key*KVD_ + g*8, &Ks[0][kk*128]);
  }

  int buf = 0;
  for (int kc = 0; kc < nk; kc += 64, buf ^= 1){
    __syncthreads();   // A: K(kc) staged; all waves done with prior Vs reads
    // stage V(kc) — latency hidden by QK phase below
    #pragma unroll
    for (int i = 0; i < 4; i++){
      int rr = wid*32 + i*8;
      int hd = rr + vrow;
      int g = vslot ^ (hd & 7);
      gl2lds16(Vg + (long)hd*S_ + kc + g*8, &Vs[rr*64]);
    }

    // ---- QK^T from Ks[buf], SWAPPED: s[t0][kt] = K_tile^T x Q_tile
    // layout: s[t0][kt][r] = S[key = kc+kt*16+quad*4+r][q = q0+t0*16+c]
    f32x4 s[2][4];
    #pragma unroll
    for (int t0 = 0; t0 < 2; t0++)
      #pragma unroll
      for (int kt = 0; kt < 4; kt++) s[t0][kt] = (f32x4){0.f,0.f,0.f,0.f};
    #pragma unroll
    for (int kt = 0; kt < 4; kt++){
      short8 kf4[4];
      #pragma unroll
      for (int f = 0; f < 4; f++)
        kf4[f] = *(const short8*)&Ks[buf][(kt*16 + c)*128 + ((f*4 + quad) ^ c)*8];
      #pragma unroll
      for (int t0 = 0; t0 < 2; t0++)
        #pragma unroll
        for (int f = 0; f < 4; f++)
          s[t0][kt] = __builtin_amdgcn_mfma_f32_16x16x32_bf16(kf4[f], qf[t0][f], s[t0][kt], 0, 0, 0);
    }
    // causal mask in transposed layout
    #pragma unroll
    for (int t0 = 0; t0 < 2; t0++){
      int qv = q0 + t0*16 + c;
      if (kc + 63 > q0 + t0*16){
        #pragma unroll
        for (int kt = 0; kt < 4; kt++){
          #pragma unroll
          for (int r = 0; r < 4; r++){
            int key = kc + kt*16 + quad*4 + r;
            if (key > qv) s[t0][kt][r] = -1e30f;
          }
        }
      }
    }

    __syncthreads();   // B: V(kc) staged (hidden by QK above)

    // prefetch K(kc+64) -> Ks[buf^1]; drained at next barrier A (hidden by PV)
    if (kc + 64 < nk){
      #pragma unroll
      for (int i = 0; i < 4; i++){
        int kk = wid*16 + i*4;
        int key = kk + skey;
        int g = kslot ^ (key & 15);
        gl2lds16(Kg + (long)(kc + 64 + key)*KVD_ + g*8, &Ks[buf^1][kk*128]);
      }
    }

    // ---- exp2 + packed P write + PV
    #pragma unroll
    for (int pp = 0; pp < 2; pp++){
      short8 vf[8];
      #pragma unroll
      for (int nt = 0; nt < 8; nt++)
        vf[nt] = *(const short8*)&Vs[(nt*16 + c)*64 + ((pp*4 + quad) ^ (c & 7))*8];
      #pragma unroll
      for (int t0 = 0; t0 < 2; t0++){
        #pragma unroll
        for (int tk = 0; tk < 2; tk++){
          f32x4 sv = s[t0][pp*2 + tk];
          float e0 = exp2f(sv[0]), e1 = exp2f(sv[1]);
          float e2 = exp2f(sv[2]), e3 = exp2f(sv[3]);
          unsigned w0, w1;
          asm("v_cvt_pk_bf16_f32 %0, %1, %2" : "=v"(w0) : "v"(e0), "v"(e1));
          asm("v_cvt_pk_bf16_f32 %0, %1, %2" : "=v"(w1) : "v"(e2), "v"(e3));
          uint2 pkv; pkv.x = w0; pkv.y = w1;
          // 4 consecutive keys for q-row c -> one 8B store
          *(uint2*)&Ps[wid][c*PSTR + tk*16 + quad*4] = pkv;
        }
        short8 pf = *(const short8*)&Ps[wid][c*PSTR + quad*8];
        #pragma unroll
        for (int nt = 0; nt < 8; nt++)
          o[t0][nt] = __builtin_amdgcn_mfma_f32_16x16x32_bf16(pf, vf[nt], o[t0][nt], 0, 0, 0);
        ol[t0] = __builtin_amdgcn_mfma_f32_16x16x32_bf16(pf, ones, ol[t0], 0, 0, 0);
      }
    }
  }

  #pragma unroll
  for (int t0 = 0; t0 < 2; t0++){
    float il[4];
    #pragma unroll
    for (int r = 0; r < 4; r++) il[r] = 1.0f / ol[t0][r];
    #pragma unroll
    for (int nt = 0; nt < 8; nt++)
      #pragma unroll
      for (int r = 0; r < 4; r++)
        ob[((long)(b*S_ + q0 + t0*16 + quad*4 + r))*H_ + h*HD_ + nt*16 + c] = f2bf(o[t0][nt][r]*il[r]);
  }
}

extern "C" void kernel_launch(void* const* d_in, const int* in_sizes, int n_in,
                              void* d_out, int out_size, void* d_ws, size_t ws_size,
                              hipStream_t stream){
  (void)in_sizes; (void)n_in; (void)out_size; (void)ws_size;
  const void* x  = d_in[0];
  const void* Wq = d_in[2];
  const void* Wk = d_in[3];
  const void* Wv = d_in[4];
  const void* Wo = d_in[5];
  char* ws = (char*)d_ws;
  size_t o = 0;
  auto alloc = [&](size_t b){ size_t r = o; o += (b + 255) & ~(size_t)255; return r; };
  size_t META = alloc(256);
  float* wsum = (float*)(ws + META);
  int*   flag = (int*)  (ws + META + 32);
  float* s_x = (float*)(ws + alloc((size_t)M_*4));
  float* s_a = (float*)(ws + alloc((size_t)M_*4));
  float* ct  = (float*)(ws + alloc((size_t)S_*64*4));
  float* st  = (float*)(ws + alloc((size_t)S_*64*4));
  s8* xq  = (s8*)(ws + alloc((size_t)M_*H_));
  s8* wqq = (s8*)(ws + alloc((size_t)H_*H_));
  s8* wkq = (s8*)(ws + alloc((size_t)KVD_*H_));
  s8* wvq = (s8*)(ws + alloc((size_t)KVD_*H_));
  s8* woq = (s8*)(ws + alloc((size_t)H_*H_));
  unsigned short* Qb = (unsigned short*)(ws + alloc((size_t)M_*NH_*HD_*2));
  unsigned short* Kb = (unsigned short*)(ws + alloc((size_t)M_*KVD_*2));
  unsigned short* Vt = (unsigned short*)(ws + alloc((size_t)M_*KVD_*2));
  unsigned short* ab = (unsigned short*)(ws + alloc((size_t)M_*H_*2));
  s8* aq = xq;   // xq dead after QKV GEMM

  hipMemsetAsync(ws + META, 0, 64, stream);
  k_detect<<<1,256,0,stream>>>((const unsigned int*)x, flag);
  k_prep<<<2048,256,0,stream>>>(Wq, Wk, Wv, Wo, flag, wsum, ct, st);
  k_wquant_all<<<2560,256,0,stream>>>(Wq, Wk, Wv, Wo, flag, wsum, wqq, wkq, wvq, woq);
  k_aquant_in<<<M_,256,0,stream>>>(x, flag, s_x, xq);

  k_gemm_qkv<<<768, 256, 0, stream>>>(xq, wqq, wkq, wvq, s_x, wsum, Qb, Kb, Vt, ct, st);

  dim3 ga(S_/32, NKV_, B_);
  k_attn_mfma<<<ga, 256, 0, stream>>>(Qb, Kb, Vt, ab);

  k_aquant_bf16<<<M_,256,0,stream>>>(ab, s_a, aq);

  k_gemm_o<<<512, 256, 0, stream>>>(aq, woq, s_a, wsum, flag, d_out, ct, st);
}